// Round 1
// baseline (4379.156 us; speedup 1.0000x reference)
//
#include <hip/hip_runtime.h>

#define TB 64
#define TT 1024
#define TC 512
#define TW 8

// Butterfly argmax over 64 lanes with jax top_k tie-breaking:
// max by value; on equal value prefer the LOWER flattened index.
__device__ __forceinline__ void argmax_bfly(float& bv, int& bf) {
  #pragma unroll
  for (int s = 1; s < 64; s <<= 1) {
    float ov = __shfl_xor(bv, s, 64);
    int   of = __shfl_xor(bf, s, 64);
    const bool better = (ov > bv) || (ov == bv && of < bf);
    bv = better ? ov : bv;
    bf = better ? of : bf;
  }
}

// Pass 1: per (b,t) row of 512 logits -> log_softmax -> top-8 (value desc,
// class asc). One wave per row, 4 waves per block. lane holds classes
// c = lane*8 + j (two float4 loads, 32B/lane coalesced).
__global__ __launch_bounds__(256) void ctc_pass1(const float* __restrict__ logits,
                                                 float* __restrict__ lp8,
                                                 unsigned short* __restrict__ cls8) {
  const int lane = threadIdx.x & 63;
  const int row  = (blockIdx.x << 2) + (threadIdx.x >> 6);  // b*TT + t
  const float* src = logits + (size_t)row * TC;

  const float4 va = *reinterpret_cast<const float4*>(src + lane * 8);
  const float4 vb = *reinterpret_cast<const float4*>(src + lane * 8 + 4);
  float v[8] = {va.x, va.y, va.z, va.w, vb.x, vb.y, vb.z, vb.w};

  // row max (exact, order-independent)
  float m = v[0];
  #pragma unroll
  for (int j = 1; j < 8; ++j) m = fmaxf(m, v[j]);
  #pragma unroll
  for (int s = 1; s < 64; s <<= 1) m = fmaxf(m, __shfl_xor(m, s, 64));

  // sum of exp(x - max), then lp = (x - max) - log(sum)   (matches
  // jax.nn.log_softmax op order; reduction-order deltas are common-mode
  // per row and cancel in beam comparisons)
  float sh[8];
  float sum = 0.f;
  #pragma unroll
  for (int j = 0; j < 8; ++j) { sh[j] = v[j] - m; sum += expf(sh[j]); }
  #pragma unroll
  for (int s = 1; s < 64; s <<= 1) sum += __shfl_xor(sum, s, 64);
  const float lse = logf(sum);

  float lp[8];
  #pragma unroll
  for (int j = 0; j < 8; ++j) lp[j] = sh[j] - lse;

  // top-8 by iterated argmax (tie -> lower class id, matching jax)
  unsigned taken = 0;
  #pragma unroll
  for (int i = 0; i < TW; ++i) {
    float bv = -INFINITY;
    int   bf = 0x7fffffff;
    #pragma unroll
    for (int j = 0; j < 8; ++j) {
      const bool ok = ((taken >> j) & 1u) == 0u;
      const float cv = ok ? lp[j] : -INFINITY;
      const int   cc = ok ? (lane * 8 + j) : 0x7fffffff;
      const bool better = (cv > bv) || (cv == bv && cc < bf);
      bv = better ? cv : bv;
      bf = better ? cc : bf;
    }
    argmax_bfly(bv, bf);                      // all lanes get winner (bv, bf)
    if ((bf >> 3) == lane) taken |= 1u << (bf & 7);
    if (lane == i) {
      lp8 [(size_t)row * 8 + i] = bv;
      cls8[(size_t)row * 8 + i] = (unsigned short)bf;
    }
  }
}

// Pass 2: one block (1 wave) per batch element. Sequential over T.
// lane = w*8 + k: candidate = score[w] + lp8[t][k]. Global top-8 of the 64
// candidates == global top-8 of all W*C candidates (per-beam top-8 pruning
// is exact, incl. ties). Backpointers kept in LDS; backtrack + CTC collapse
// at the end.
__global__ __launch_bounds__(64) void ctc_pass2(const float* __restrict__ lp8,
                                                const unsigned short* __restrict__ cls8,
                                                float* __restrict__ out) {
  __shared__ unsigned short bp[TT * TW];  // (parent<<9)|cls, 16 KB
  __shared__ int   seq[TT];               // 4 KB
  __shared__ float outb[TT];              // 4 KB

  const int b    = blockIdx.x;
  const int lane = threadIdx.x;
  const int w    = lane >> 3;
  const int k    = lane & 7;
  const size_t base = (size_t)b * TT * 8;

  float myscore = (w == 0) ? 0.0f : -1e30f;   // matches init_scores
  float lpv = lp8 [base + k];
  int   cv  = cls8[base + k];

  for (int t = 0; t < TT; ++t) {
    // software-pipelined prefetch of next step's pruned row (hides L2/L3 latency)
    float lpn = 0.f; int cn = 0;
    if (t + 1 < TT) {
      lpn = lp8 [base + (size_t)(t + 1) * 8 + k];
      cn  = cls8[base + (size_t)(t + 1) * 8 + k];
    }

    const float cand = myscore + lpv;         // fp32, same op as reference
    const int   flat = (w << 9) | cv;         // w*C + c  (jax tie-break key)
    bool taken = false;

    #pragma unroll
    for (int i = 0; i < TW; ++i) {
      float bv = taken ? -INFINITY : cand;
      int   bf = taken ? 0x7fffffff : flat;
      argmax_bfly(bv, bf);                    // winner i in all lanes
      if (bf == flat) taken = true;           // flats are unique; owner masks itself
      if (w == i) myscore = bv;               // new beam i score
      if (lane == i) bp[t * TW + i] = (unsigned short)bf;
    }

    lpv = lpn; cv = cn;
  }

  __syncthreads();

  // backtrack best beam (beam 0 = top-ranked, as reference takes seqs[:,0,:])
  if (lane == 0) {
    int w0 = 0;
    for (int t = TT - 1; t >= 0; --t) {
      const int vv = bp[t * TW + w0];
      seq[t] = vv & 511;
      w0 = vv >> 9;
    }
  }
  __syncthreads();

  for (int i = lane; i < TT; i += 64) outb[i] = -1.0f;
  __syncthreads();

  // CTC collapse: keep t iff nonblank and != previous NON-BLANK class
  int n = 0;
  if (lane == 0) {
    int prev = -1;
    for (int t = 0; t < TT; ++t) {
      const int c = seq[t];
      if (c != 0) {
        if (c != prev) outb[n++] = (float)c;
        prev = c;
      }
    }
  }
  __syncthreads();
  n = __shfl(n, 0, 64);

  float* dec = out + (size_t)b * TT;
  for (int i = lane; i < TT; i += 64) dec[i] = outb[i];
  if (lane == 0) {
    out[TB * TT + b]      = (float)n;    // lengths
    out[TB * TT + TB + b] = myscore;     // lane 0 holds beam-0 final score
  }
}

extern "C" void kernel_launch(void* const* d_in, const int* in_sizes, int n_in,
                              void* d_out, int out_size, void* d_ws, size_t ws_size,
                              hipStream_t stream) {
  (void)in_sizes; (void)n_in; (void)out_size; (void)ws_size;
  const float* logits = (const float*)d_in[0];

  float* lp8 = (float*)d_ws;                                   // 2 MB
  unsigned short* cls8 =
      (unsigned short*)((char*)d_ws + (size_t)TB * TT * 8 * sizeof(float)); // +1 MB

  ctc_pass1<<<dim3((TB * TT) / 4), dim3(256), 0, stream>>>(logits, lp8, cls8);
  ctc_pass2<<<dim3(TB), dim3(64), 0, stream>>>(lp8, cls8, (float*)d_out);
}

// Round 2
// 842.588 us; speedup vs baseline: 5.1973x; 5.1973x over previous
//
#include <hip/hip_runtime.h>

#define TB 64
#define TT 1024
#define TC 512
#define TW 8

typedef unsigned long long u64;

// ---------------------------------------------------------------------------
// Pass 1: per (b,t) row of 512 logits -> log_softmax -> top-8 (value desc,
// class asc). One wave per row, 4 waves per block. Output packed int2:
// {float bits of lp, class id}, in rank order — each row's list is sorted by
// the exact jax top_k comparator (value desc, index asc).
// ---------------------------------------------------------------------------

__device__ __forceinline__ void argmax_bfly(float& bv, int& bf) {
  #pragma unroll
  for (int s = 1; s < 64; s <<= 1) {
    float ov = __shfl_xor(bv, s, 64);
    int   of = __shfl_xor(bf, s, 64);
    const bool better = (ov > bv) || (ov == bv && of < bf);
    bv = better ? ov : bv;
    bf = better ? of : bf;
  }
}

__global__ __launch_bounds__(256) void ctc_pass1(const float* __restrict__ logits,
                                                 int2* __restrict__ pk) {
  const int lane = threadIdx.x & 63;
  const int row  = (blockIdx.x << 2) + (threadIdx.x >> 6);  // b*TT + t
  const float* src = logits + (size_t)row * TC;

  const float4 va = *reinterpret_cast<const float4*>(src + lane * 8);
  const float4 vb = *reinterpret_cast<const float4*>(src + lane * 8 + 4);
  float v[8] = {va.x, va.y, va.z, va.w, vb.x, vb.y, vb.z, vb.w};

  // row max (exact, order-independent)
  float m = v[0];
  #pragma unroll
  for (int j = 1; j < 8; ++j) m = fmaxf(m, v[j]);
  #pragma unroll
  for (int s = 1; s < 64; s <<= 1) m = fmaxf(m, __shfl_xor(m, s, 64));

  // lp = (x - max) - log(sum(exp(x - max))); reduction-order deltas are
  // common-mode per row and cancel in beam comparisons.
  float sh[8];
  float sum = 0.f;
  #pragma unroll
  for (int j = 0; j < 8; ++j) { sh[j] = v[j] - m; sum += expf(sh[j]); }
  #pragma unroll
  for (int s = 1; s < 64; s <<= 1) sum += __shfl_xor(sum, s, 64);
  const float lse = logf(sum);

  float lp[8];
  #pragma unroll
  for (int j = 0; j < 8; ++j) lp[j] = sh[j] - lse;

  // top-8 by iterated argmax (tie -> lower class id, matching jax top_k)
  unsigned taken = 0;
  #pragma unroll
  for (int i = 0; i < TW; ++i) {
    float bv = -INFINITY;
    int   bf = 0x7fffffff;
    #pragma unroll
    for (int j = 0; j < 8; ++j) {
      const bool ok = ((taken >> j) & 1u) == 0u;
      const float cv = ok ? lp[j] : -INFINITY;
      const int   cc = ok ? (lane * 8 + j) : 0x7fffffff;
      const bool better = (cv > bv) || (cv == bv && cc < bf);
      bv = better ? cv : bv;
      bf = better ? cc : bf;
    }
    argmax_bfly(bv, bf);
    if ((bf >> 3) == lane) taken |= 1u << (bf & 7);
    if (lane == i) pk[(size_t)row * 8 + i] = make_int2(__float_as_int(bv), bf);
  }
}

// ---------------------------------------------------------------------------
// Pass 2: one wave per batch element; sequential over T but with a
// merge-prune selection network instead of 8 iterated 6-stage argmaxes.
//
// Key packing (monotone total order == jax top_k order):
//   u    = ordered-uint transform of the fp32 candidate (value desc)
//   K    = (u << 12) | (~flat & 0xFFF)        flat = w*512 + cls (asc on ties)
// Flats are unique per step -> strict total order, no ambiguous ties.
//
// Network: per-beam 8-lists arrive sorted (pass 1). Merge-prune tree:
//   CE(lane^15)  -> top-8 of beam pairs (bitonic)   -> sort8 (xor 4,2,1)
//   CE(lane^23)  -> top-8 of beam quads             -> sort8
//   CE(lane^39)  -> top-8 of all 8 beams            -> sort8
// xor1/xor2 use DPP quad_perm (VALU-latency); xor4/15/23/39 use shfl.
// Every 8-lane group ends holding the identical sorted top-8, so the new
// score for beam w is one intra-group shuffle away.
// ---------------------------------------------------------------------------

template<int M>
__device__ __forceinline__ void ce_shfl(u64& K, bool keepmax) {
  const u64 OK = __shfl_xor(K, M, 64);
  const bool take = (OK > K) == keepmax;
  K = take ? OK : K;
}

#define QP_XOR1 0xB1  // quad_perm [1,0,3,2]
#define QP_XOR2 0x4E  // quad_perm [2,3,0,1]

template<int CTRL>
__device__ __forceinline__ void ce_dpp(u64& K, bool keepmax) {
  const unsigned lo = (unsigned)__builtin_amdgcn_mov_dpp((int)(unsigned)(K & 0xFFFFFFFFull),
                                                         CTRL, 0xf, 0xf, true);
  const unsigned hi = (unsigned)__builtin_amdgcn_mov_dpp((int)(unsigned)(K >> 32),
                                                         CTRL, 0xf, 0xf, true);
  const u64 OK = ((u64)hi << 32) | lo;
  const bool take = (OK > K) == keepmax;
  K = take ? OK : K;
}

__device__ __forceinline__ void sort8(u64& K, int lane) {
  ce_shfl<4>(K, (lane & 4) == 0);
  ce_dpp<QP_XOR2>(K, (lane & 2) == 0);
  ce_dpp<QP_XOR1>(K, (lane & 1) == 0);
}

__global__ __launch_bounds__(64) void ctc_pass2(const int2* __restrict__ pk,
                                                float* __restrict__ out) {
  __shared__ unsigned short bp[TT * TW];  // (parent<<9)|cls, 16 KB
  __shared__ int   seq[TT];               // 4 KB
  __shared__ float outb[TT];              // 4 KB

  const int b    = blockIdx.x;
  const int lane = threadIdx.x;
  const int w    = lane >> 3;
  const int k    = lane & 7;
  const size_t base = (size_t)b * TT * 8;

  float myscore = (w == 0) ? 0.0f : -1e30f;   // matches init_scores
  int2 cur = pk[base + k];

  for (int t = 0; t < TT; ++t) {
    // prefetch next step's pruned row (clamped; off the critical chain)
    const int tn = (t + 1 < TT) ? (t + 1) : (TT - 1);
    const int2 nxt = pk[base + (size_t)tn * 8 + k];

    // candidate = score[w] + lp[t][k]  (fp32, same op as reference)
    const float cand = myscore + __int_as_float(cur.x);
    unsigned u = __float_as_uint(cand);
    u ^= (unsigned)(((int)u >> 31) | 0x80000000);     // ordered-uint transform
    const int flat = (w << 9) | cur.y;                // w*C + c (jax tie key)
    u64 K = ((u64)u << 12) | (unsigned)((~flat) & 0xFFF);

    ce_shfl<15>(K, true);  sort8(K, lane);   // beams {2g,2g+1}
    ce_shfl<23>(K, true);  sort8(K, lane);   // beams {4g..4g+3}
    ce_shfl<39>(K, true);  sort8(K, lane);   // all 8 beams

    // lane holds rank (lane&7) of the global top-8 (duplicated per 8-group)
    if (lane < 8) bp[t * TW + lane] = (unsigned short)((~K) & 0xFFF);

    // new score for this lane's beam w: rank-w key from own 8-group
    const u64 KW = __shfl(K, (lane & 56) | w, 64);
    unsigned uw = (unsigned)(KW >> 12);
    uw = (uw & 0x80000000u) ? (uw ^ 0x80000000u) : ~uw;  // inverse transform
    myscore = __uint_as_float(uw);

    cur = nxt;
  }

  __syncthreads();

  // backtrack best beam (beam 0 = top-ranked, as reference takes seqs[:,0,:])
  if (lane == 0) {
    int w0 = 0;
    for (int t = TT - 1; t >= 0; --t) {
      const int vv = bp[t * TW + w0];
      seq[t] = vv & 511;
      w0 = vv >> 9;
    }
  }
  __syncthreads();

  for (int i = lane; i < TT; i += 64) outb[i] = -1.0f;
  __syncthreads();

  // CTC collapse: keep t iff nonblank and != previous NON-BLANK class
  int n = 0;
  if (lane == 0) {
    int prev = -1;
    for (int t = 0; t < TT; ++t) {
      const int c = seq[t];
      if (c != 0) {
        if (c != prev) outb[n++] = (float)c;
        prev = c;
      }
    }
  }
  __syncthreads();
  n = __shfl(n, 0, 64);

  float* dec = out + (size_t)b * TT;
  for (int i = lane; i < TT; i += 64) dec[i] = outb[i];
  if (lane == 0) {
    out[TB * TT + b]      = (float)n;    // lengths
    out[TB * TT + TB + b] = myscore;     // lane 0 carries beam-0 score
  }
}

extern "C" void kernel_launch(void* const* d_in, const int* in_sizes, int n_in,
                              void* d_out, int out_size, void* d_ws, size_t ws_size,
                              hipStream_t stream) {
  (void)in_sizes; (void)n_in; (void)out_size; (void)ws_size;
  const float* logits = (const float*)d_in[0];

  int2* pk = (int2*)d_ws;   // 64*1024*8 * 8 B = 4 MB packed {lp bits, cls}

  ctc_pass1<<<dim3((TB * TT) / 4), dim3(256), 0, stream>>>(logits, pk);
  ctc_pass2<<<dim3(TB), dim3(64), 0, stream>>>(pk, (float*)d_out);
}

// Round 3
// 692.737 us; speedup vs baseline: 6.3215x; 1.2163x over previous
//
#include <hip/hip_runtime.h>

#define TB 64
#define TT 1024
#define TC 512
#define TW 8

typedef unsigned long long u64;
typedef unsigned int uint;

// ===========================================================================
// Pass 1 (unchanged from round 2 — lp arithmetic bitwise-stable)
// ===========================================================================

__device__ __forceinline__ void argmax_bfly(float& bv, int& bf) {
  #pragma unroll
  for (int s = 1; s < 64; s <<= 1) {
    float ov = __shfl_xor(bv, s, 64);
    int   of = __shfl_xor(bf, s, 64);
    const bool better = (ov > bv) || (ov == bv && of < bf);
    bv = better ? ov : bv;
    bf = better ? of : bf;
  }
}

__global__ __launch_bounds__(256) void ctc_pass1(const float* __restrict__ logits,
                                                 int2* __restrict__ pk) {
  const int lane = threadIdx.x & 63;
  const int row  = (blockIdx.x << 2) + (threadIdx.x >> 6);  // b*TT + t
  const float* src = logits + (size_t)row * TC;

  const float4 va = *reinterpret_cast<const float4*>(src + lane * 8);
  const float4 vb = *reinterpret_cast<const float4*>(src + lane * 8 + 4);
  float v[8] = {va.x, va.y, va.z, va.w, vb.x, vb.y, vb.z, vb.w};

  float m = v[0];
  #pragma unroll
  for (int j = 1; j < 8; ++j) m = fmaxf(m, v[j]);
  #pragma unroll
  for (int s = 1; s < 64; s <<= 1) m = fmaxf(m, __shfl_xor(m, s, 64));

  float sh[8];
  float sum = 0.f;
  #pragma unroll
  for (int j = 0; j < 8; ++j) { sh[j] = v[j] - m; sum += expf(sh[j]); }
  #pragma unroll
  for (int s = 1; s < 64; s <<= 1) sum += __shfl_xor(sum, s, 64);
  const float lse = logf(sum);

  float lp[8];
  #pragma unroll
  for (int j = 0; j < 8; ++j) lp[j] = sh[j] - lse;

  unsigned taken = 0;
  #pragma unroll
  for (int i = 0; i < TW; ++i) {
    float bv = -INFINITY;
    int   bf = 0x7fffffff;
    #pragma unroll
    for (int j = 0; j < 8; ++j) {
      const bool ok = ((taken >> j) & 1u) == 0u;
      const float cv = ok ? lp[j] : -INFINITY;
      const int   cc = ok ? (lane * 8 + j) : 0x7fffffff;
      const bool better = (cv > bv) || (cv == bv && cc < bf);
      bv = better ? cv : bv;
      bf = better ? cc : bf;
    }
    argmax_bfly(bv, bf);
    if ((bf >> 3) == lane) taken |= 1u << (bf & 7);
    if (lane == i) pk[(size_t)row * 8 + i] = make_int2(__float_as_int(bv), bf);
  }
}

// ===========================================================================
// Pass 2: all-VALU selection network (DPP quad_perm / row_ror / mirrors +
// v_permlane16/32_swap). No ds_bpermute anywhere on the critical chain.
// ===========================================================================

template<int CTRL>
__device__ __forceinline__ u64 dppmov64(u64 x) {
  uint lo = (uint)__builtin_amdgcn_mov_dpp((int)(uint)x,         CTRL, 0xf, 0xf, true);
  uint hi = (uint)__builtin_amdgcn_mov_dpp((int)(uint)(x >> 32), CTRL, 0xf, 0xf, true);
  return ((u64)hi << 32) | lo;
}

#define DPP_XOR1  0xB1   // quad_perm [1,0,3,2]
#define DPP_XOR2  0x4E   // quad_perm [2,3,0,1]
#define DPP_XOR3  0x1B   // quad_perm [3,2,1,0]
#define DPP_HMIR  0x141  // row_half_mirror (xor 7)
#define DPP_ROR8  0x128  // row_ror:8 == xor 8 within a 16-lane row

__device__ __forceinline__ u64 dpp_xor4(u64 x) {          // xor3 then xor7 => xor4
  return dppmov64<DPP_HMIR>(dppmov64<DPP_XOR3>(x));
}

// permlane swaps return the unordered pair {own, partner(lane^16/32)}
__device__ __forceinline__ void plswap16(u64 k, u64& X, u64& Y) {
  uint a0 = (uint)k, b0 = (uint)k, a1 = (uint)(k >> 32), b1 = (uint)(k >> 32);
  asm("v_permlane16_swap_b32 %0, %1" : "+v"(a0), "+v"(b0));
  asm("v_permlane16_swap_b32 %0, %1" : "+v"(a1), "+v"(b1));
  X = ((u64)a1 << 32) | a0;
  Y = ((u64)b1 << 32) | b0;
}
__device__ __forceinline__ void plswap32(u64 k, u64& X, u64& Y) {
  uint a0 = (uint)k, b0 = (uint)k, a1 = (uint)(k >> 32), b1 = (uint)(k >> 32);
  asm("v_permlane32_swap_b32 %0, %1" : "+v"(a0), "+v"(b0));
  asm("v_permlane32_swap_b32 %0, %1" : "+v"(a1), "+v"(b1));
  X = ((u64)a1 << 32) | a0;
  Y = ((u64)b1 << 32) | b0;
}

__device__ __forceinline__ u64 umax64(u64 a, u64 b) { return a > b ? a : b; }
// compare-exchange on an (unordered) pair: keep -> max, !keep -> min
__device__ __forceinline__ u64 cedir(u64 a, u64 b, bool keep) {
  return ((a > b) == keep) ? a : b;
}

__device__ __forceinline__ uint ford(float f) {           // float -> ordered uint
  uint u = __float_as_uint(f);
  return u ^ ((uint)(((int)u) >> 31) | 0x80000000u);
}
__device__ __forceinline__ float finv(uint u) {           // inverse
  return __uint_as_float(u ^ ((~(uint)(((int)u) >> 31)) | 0x80000000u));
}

__global__ __launch_bounds__(64) void ctc_pass2(const int2* __restrict__ pk,
                                                float* __restrict__ out) {
  __shared__ unsigned short bp[TT * TW];  // (parent<<9)|cls, 16 KB
  __shared__ int   seq[TT];
  __shared__ float outb[TT];

  const int b    = blockIdx.x;
  const int lane = threadIdx.x;
  const int lo   = lane & 7;
  const int hi   = lane >> 3;
  const size_t base = (size_t)b * TT * 8;

  // pre-reversed load indices give alternating per-beam list directions
  const int idxB = (hi & 1) ? (7 - lo) : lo;   // even steps: beams along hi, lists along lo
  const int idxA = (lo & 1) ? (7 - hi) : hi;   // odd  steps: beams along lo, lists along hi
  const int2* ptrB = pk + base + idxB;
  const int2* ptrA = pk + base + idxA;

  // cleanup-direction booleans (loop-invariant, per lane)
  const bool dB1 = ((hi >> 1) & 1) == 0, dB2 = ((hi >> 2) & 1) == 0;
  const bool dA1 = ((lo >> 1) & 1) == 0, dA2 = ((lo >> 2) & 1) == 0;
  const bool l4 = (lo & 4) == 0, l2 = (lo & 2) == 0, l1 = (lo & 1) == 0;
  const bool h4 = (hi & 4) == 0, h2 = (hi & 2) == 0, h1 = (hi & 1) == 0;
  const bool kB1_4 = (l4 == dB1), kB1_2 = (l2 == dB1), kB1_1 = (l1 == dB1);
  const bool kB2_4 = (l4 == dB2), kB2_2 = (l2 == dB2), kB2_1 = (l1 == dB2);
  const bool kA1_4 = (h4 == dA1), kA1_2 = (h2 == dA1), kA1_1 = (h1 == dA1);
  const bool kA2_4 = (h4 == dA2), kA2_2 = (h2 == dA2), kA2_1 = (h1 == dA2);

  float s = (hi == 0) ? 0.0f : -1e30f;  // matches init_scores (step 0 is a B step)

  // 2-iteration-deep prefetch (covers L2/L3 latency of the 8 B step rows)
  int2 vB = ptrB[0],  vA = ptrA[8];
  int2 wB = ptrB[16], wA = ptrA[24];

  for (int t = 0; t < TT; t += 2) {
    const int tB = (t + 4 < TT) ? (t + 4) : (TT - 2);
    const int tA = (t + 5 < TT) ? (t + 5) : (TT - 1);
    const int2 nB = ptrB[tB * 8];
    const int2 nA = ptrA[tA * 8];

    // ---- step t (variant B: beams along hi, lists along lo) ----
    {
      const uint flat = ((uint)hi << 9) | (uint)vB.y;
      const uint tie  = (~flat) & 0xFFFu;
      const uint u    = ford(s + __int_as_float(vB.x));
      u64 K = ((u64)u << 12) | tie;
      u64 P, X, Y;
      P = dppmov64<DPP_ROR8>(K); K = umax64(K, P);          // merge beams hi^1 (mask 8)
      P = dpp_xor4(K);           K = cedir(K, P, kB1_4);    // cleanup along lo
      P = dppmov64<DPP_XOR2>(K); K = cedir(K, P, kB1_2);
      P = dppmov64<DPP_XOR1>(K); K = cedir(K, P, kB1_1);
      plswap16(K, X, Y);         K = umax64(X, Y);          // merge mask 16
      P = dpp_xor4(K);           K = cedir(K, P, kB2_4);
      P = dppmov64<DPP_XOR2>(K); K = cedir(K, P, kB2_2);
      P = dppmov64<DPP_XOR1>(K); K = cedir(K, P, kB2_1);
      plswap32(K, X, Y);         K = umax64(X, Y);          // merge mask 32
      P = dpp_xor4(K);           K = cedir(K, P, l4);       // final: sorted desc, rank = lo
      P = dppmov64<DPP_XOR2>(K); K = cedir(K, P, l2);
      P = dppmov64<DPP_XOR1>(K); K = cedir(K, P, l1);
      if (hi == 0) bp[t * TW + lo] = (unsigned short)((~(uint)K) & 0xFFFu);
      s = finv((uint)(K >> 12));                            // lane's next beam = lo, rank lo
    }
    // ---- step t+1 (variant A: beams along lo, lists along hi) ----
    {
      const uint flat = ((uint)lo << 9) | (uint)vA.y;
      const uint tie  = (~flat) & 0xFFFu;
      const uint u    = ford(s + __int_as_float(vA.x));
      u64 K = ((u64)u << 12) | tie;
      u64 P, X, Y;
      P = dppmov64<DPP_XOR1>(K); K = umax64(K, P);          // merge beams lo^1 (mask 1)
      plswap32(K, X, Y);         K = cedir(X, Y, kA1_4);    // cleanup along hi (dist 4)
      plswap16(K, X, Y);         K = cedir(X, Y, kA1_2);    // (dist 2)
      P = dppmov64<DPP_ROR8>(K); K = cedir(K, P, kA1_1);    // (dist 1)
      P = dppmov64<DPP_XOR2>(K); K = umax64(K, P);          // merge mask 2
      plswap32(K, X, Y);         K = cedir(X, Y, kA2_4);
      plswap16(K, X, Y);         K = cedir(X, Y, kA2_2);
      P = dppmov64<DPP_ROR8>(K); K = cedir(K, P, kA2_1);
      P = dpp_xor4(K);           K = umax64(K, P);          // merge mask 4
      plswap32(K, X, Y);         K = cedir(X, Y, h4);       // final: rank = hi
      plswap16(K, X, Y);         K = cedir(X, Y, h2);
      P = dppmov64<DPP_ROR8>(K); K = cedir(K, P, h1);
      if (lo == 0) bp[(t + 1) * TW + hi] = (unsigned short)((~(uint)K) & 0xFFFu);
      s = finv((uint)(K >> 12));                            // lane's next beam = hi, rank hi
    }
    vB = wB; vA = wA; wB = nB; wA = nA;
  }

  __syncthreads();

  // backtrack best beam (rank 0 at t = TT-1)
  if (lane == 0) {
    int w0 = 0;
    for (int t = TT - 1; t >= 0; --t) {
      const int vv = bp[t * TW + w0];
      seq[t] = vv & 511;
      w0 = vv >> 9;
    }
  }
  __syncthreads();

  for (int i = lane; i < TT; i += 64) outb[i] = -1.0f;
  __syncthreads();

  // CTC collapse: keep t iff nonblank and != previous NON-BLANK class
  int n = 0;
  if (lane == 0) {
    int prev = -1;
    for (int t = 0; t < TT; ++t) {
      const int c = seq[t];
      if (c != 0) {
        if (c != prev) outb[n++] = (float)c;
        prev = c;
      }
    }
  }
  __syncthreads();
  n = __shfl(n, 0, 64);

  float* dec = out + (size_t)b * TT;
  for (int i = lane; i < TT; i += 64) dec[i] = outb[i];
  if (lane == 0) {
    out[TB * TT + b]      = (float)n;   // lengths
    out[TB * TT + TB + b] = s;          // lane 0 holds rank-0 (beam 0) score
  }
}

extern "C" void kernel_launch(void* const* d_in, const int* in_sizes, int n_in,
                              void* d_out, int out_size, void* d_ws, size_t ws_size,
                              hipStream_t stream) {
  (void)in_sizes; (void)n_in; (void)out_size; (void)ws_size;
  const float* logits = (const float*)d_in[0];

  int2* pk = (int2*)d_ws;   // 64*1024*8 * 8 B = 4 MB packed {lp bits, cls}

  ctc_pass1<<<dim3((TB * TT) / 4), dim3(256), 0, stream>>>(logits, pk);
  ctc_pass2<<<dim3(TB), dim3(64), 0, stream>>>(pk, (float*)d_out);
}

// Round 7
// 515.148 us; speedup vs baseline: 8.5008x; 1.3447x over previous
//
#include <hip/hip_runtime.h>

#define TB 64
#define TT 1024
#define TC 512
#define TW 8

typedef unsigned long long u64;
typedef unsigned int uint;
typedef __attribute__((ext_vector_type(2))) unsigned int uint2v;

// ===========================================================================
// Monotone f64 keys: key = (1<<62) | (ford(value) << 12) | (~flat & 0xFFF).
// Bit 62 makes the double normal (exp=0x400): no denorm/NaN hazards; for
// positive doubles, value order == bit-pattern order, so v_max_f64/v_min_f64
// implement exact (value desc, flat asc) compare-exchanges in ONE instruction.
// ===========================================================================

#define KOFF 0x4000000000000000ull

__device__ __forceinline__ double kd(u64 k) { return __longlong_as_double((long long)k); }
__device__ __forceinline__ u64 dk(double d) { return (u64)__double_as_longlong(d); }

__device__ __forceinline__ u64 kmax(u64 a, u64 b) { return dk(fmax(kd(a), kd(b))); }
__device__ __forceinline__ u64 kmin(u64 a, u64 b) { return dk(fmin(kd(a), kd(b))); }
// keep ? max : min  (operands may be an unordered pair)
__device__ __forceinline__ u64 ksel(u64 a, u64 b, bool keep) {
  double A = kd(a), B = kd(b);
  return dk(keep ? fmax(A, B) : fmin(A, B));
}

__device__ __forceinline__ uint ford(float f) {           // float -> ordered uint
  uint u = __float_as_uint(f);
  return u ^ ((uint)(((int)u) >> 31) | 0x80000000u);
}
__device__ __forceinline__ float finv(uint u) {           // inverse
  return __uint_as_float(u ^ ((~(uint)(((int)u) >> 31)) | 0x80000000u));
}

#define DPP_XOR1  0xB1   // quad_perm [1,0,3,2]
#define DPP_XOR2  0x4E   // quad_perm [2,3,0,1]
#define DPP_XOR3  0x1B   // quad_perm [3,2,1,0]
#define DPP_HMIR  0x141  // row_half_mirror (xor 7)
#define DPP_ROR8  0x128  // row_ror:8 == xor 8 within a 16-lane row

template<int CTRL>
__device__ __forceinline__ u64 dppmov64(u64 x) {
  uint lo = (uint)__builtin_amdgcn_mov_dpp((int)(uint)x,         CTRL, 0xf, 0xf, true);
  uint hi = (uint)__builtin_amdgcn_mov_dpp((int)(uint)(x >> 32), CTRL, 0xf, 0xf, true);
  return ((u64)hi << 32) | lo;
}
__device__ __forceinline__ u64 dpp_xor4(u64 x) {          // xor3 then xor7 => xor4
  return dppmov64<DPP_HMIR>(dppmov64<DPP_XOR3>(x));
}

template<int CTRL>
__device__ __forceinline__ float dppf(float x) {
  return __uint_as_float((uint)__builtin_amdgcn_mov_dpp((int)__float_as_uint(x),
                                                        CTRL, 0xf, 0xf, true));
}
__device__ __forceinline__ float dppf_xor4(float x) {
  return dppf<DPP_HMIR>(dppf<DPP_XOR3>(x));
}

// ---------------------------------------------------------------------------
// permlane swaps: return the unordered pair {own, partner(lane^16/32)}.
// ROUND-6 FIX: use the gfx950 BUILTINS (compiler-managed hazard NOPs and
// register allocation) instead of hand asm. v_permlane*_swap reads its
// operands through the DPP/crossbar path: a VALU write followed 0-1 cycles
// later by a crossbar read of the same VGPR is a HW hazard whose wait states
// only the compiler inserts — inside inline asm nobody inserts them, which
// is the unified explanation for r3-pass/r4-fail/r6-fail. The builtin
// returns the post-swap {vdst, vsrc} pair; with both inputs = K this is
// exactly the unordered {own, partner} pair the network consumes.
// ---------------------------------------------------------------------------
__device__ __forceinline__ void plswap16(u64 k, u64& X, u64& Y) {
  const uint2v lo = __builtin_amdgcn_permlane16_swap((uint)k, (uint)k, false, false);
  const uint2v hi = __builtin_amdgcn_permlane16_swap((uint)(k >> 32), (uint)(k >> 32),
                                                     false, false);
  X = ((u64)hi[0] << 32) | lo[0];
  Y = ((u64)hi[1] << 32) | lo[1];
}
__device__ __forceinline__ void plswap32(u64 k, u64& X, u64& Y) {
  const uint2v lo = __builtin_amdgcn_permlane32_swap((uint)k, (uint)k, false, false);
  const uint2v hi = __builtin_amdgcn_permlane32_swap((uint)(k >> 32), (uint)(k >> 32),
                                                     false, false);
  X = ((u64)hi[0] << 32) | lo[0];
  Y = ((u64)hi[1] << 32) | lo[1];
}
__device__ __forceinline__ void plswap16f(float k, float& X, float& Y) {
  const uint2v r = __builtin_amdgcn_permlane16_swap(__float_as_uint(k),
                                                    __float_as_uint(k), false, false);
  X = __uint_as_float(r[0]); Y = __uint_as_float(r[1]);
}
__device__ __forceinline__ void plswap32f(float k, float& X, float& Y) {
  const uint2v r = __builtin_amdgcn_permlane32_swap(__float_as_uint(k),
                                                    __float_as_uint(k), false, false);
  X = __uint_as_float(r[0]); Y = __uint_as_float(r[1]);
}
// isolate the partner value from an unordered pair (keys are unique)
__device__ __forceinline__ u64 other(u64 own, u64 X, u64 Y) {
  return (X == own) ? Y : X;
}

// in-register compare-exchanges
__device__ __forceinline__ void ce_desc(u64& a, u64& b) {
  u64 mx = kmax(a, b), mn = kmin(a, b); a = mx; b = mn;
}
__device__ __forceinline__ void ce_asc(u64& a, u64& b) {
  u64 mx = kmax(a, b), mn = kmin(a, b); a = mn; b = mx;
}

// ===========================================================================
// Pass 1: per (b,t) row of 512 logits -> log_softmax -> top-8 sorted by
// (value desc, class asc). One wave/row. In-reg sort8 + 6-level cross-lane
// merge-prune tree; all-VALU (no ds_bpermute).
// ===========================================================================

// prune top-8 of two sorted-desc 8-lists (ours + partner's), re-sort desc.
__device__ __forceinline__ void prune_cleanup(u64 k[8], const u64 p[8]) {
  u64 c[8];
  #pragma unroll
  for (int j = 0; j < 8; ++j) c[j] = kmax(k[j], p[7 - j]);   // bitonic split
  ce_desc(c[0], c[4]); ce_desc(c[1], c[5]); ce_desc(c[2], c[6]); ce_desc(c[3], c[7]);
  ce_desc(c[0], c[2]); ce_desc(c[1], c[3]); ce_desc(c[4], c[6]); ce_desc(c[5], c[7]);
  ce_desc(c[0], c[1]); ce_desc(c[2], c[3]); ce_desc(c[4], c[5]); ce_desc(c[6], c[7]);
  #pragma unroll
  for (int j = 0; j < 8; ++j) k[j] = c[j];
}

__global__ __launch_bounds__(256) void ctc_pass1(const float* __restrict__ logits,
                                                 int2* __restrict__ pk) {
  const int lane = threadIdx.x & 63;
  const int row  = (blockIdx.x << 2) + (threadIdx.x >> 6);  // b*TT + t
  const float* src = logits + (size_t)row * TC;

  const float4 va = *reinterpret_cast<const float4*>(src + lane * 8);
  const float4 vb = *reinterpret_cast<const float4*>(src + lane * 8 + 4);
  float v[8] = {va.x, va.y, va.z, va.w, vb.x, vb.y, vb.z, vb.w};

  // row max — same butterfly partner pairing as rounds 1-3 (bitwise stable)
  float m = v[0];
  #pragma unroll
  for (int j = 1; j < 8; ++j) m = fmaxf(m, v[j]);
  m = fmaxf(m, dppf<DPP_XOR1>(m));
  m = fmaxf(m, dppf<DPP_XOR2>(m));
  m = fmaxf(m, dppf_xor4(m));
  m = fmaxf(m, dppf<DPP_ROR8>(m));
  { float X, Y; plswap16f(m, X, Y); m = fmaxf(X, Y); }
  { float X, Y; plswap32f(m, X, Y); m = fmaxf(X, Y); }

  float sh[8];
  float sum = 0.f;
  #pragma unroll
  for (int j = 0; j < 8; ++j) { sh[j] = v[j] - m; sum += expf(sh[j]); }
  sum += dppf<DPP_XOR1>(sum);
  sum += dppf<DPP_XOR2>(sum);
  sum += dppf_xor4(sum);
  sum += dppf<DPP_ROR8>(sum);
  { float X, Y; plswap16f(sum, X, Y); sum = X + Y; }
  { float X, Y; plswap32f(sum, X, Y); sum = X + Y; }
  const float lse = logf(sum);

  // keys: (value, class) with exact jax top_k order
  u64 k[8];
  #pragma unroll
  for (int j = 0; j < 8; ++j) {
    const float lp = sh[j] - lse;
    const uint cls = (uint)((lane << 3) + j);
    k[j] = KOFF | ((u64)ford(lp) << 12) | ((~cls) & 0xFFFu);
  }

  // bitonic sort8 desc (24 CEs)
  ce_desc(k[0], k[1]); ce_asc(k[2], k[3]); ce_desc(k[4], k[5]); ce_asc(k[6], k[7]);
  ce_desc(k[0], k[2]); ce_desc(k[1], k[3]); ce_asc(k[4], k[6]); ce_asc(k[5], k[7]);
  ce_desc(k[0], k[1]); ce_desc(k[2], k[3]); ce_asc(k[4], k[5]); ce_asc(k[6], k[7]);
  ce_desc(k[0], k[4]); ce_desc(k[1], k[5]); ce_desc(k[2], k[6]); ce_desc(k[3], k[7]);
  ce_desc(k[0], k[2]); ce_desc(k[1], k[3]); ce_desc(k[4], k[6]); ce_desc(k[5], k[7]);
  ce_desc(k[0], k[1]); ce_desc(k[2], k[3]); ce_desc(k[4], k[5]); ce_desc(k[6], k[7]);

  // 6-level cross-lane merge-prune (d = 1,2,4,8 via DPP; 16,32 via permlane)
  u64 p[8];
  #pragma unroll
  for (int j = 0; j < 8; ++j) p[j] = dppmov64<DPP_XOR1>(k[j]);
  prune_cleanup(k, p);
  #pragma unroll
  for (int j = 0; j < 8; ++j) p[j] = dppmov64<DPP_XOR2>(k[j]);
  prune_cleanup(k, p);
  #pragma unroll
  for (int j = 0; j < 8; ++j) p[j] = dpp_xor4(k[j]);
  prune_cleanup(k, p);
  #pragma unroll
  for (int j = 0; j < 8; ++j) p[j] = dppmov64<DPP_ROR8>(k[j]);
  prune_cleanup(k, p);
  #pragma unroll
  for (int j = 0; j < 8; ++j) { u64 X, Y; plswap16(k[j], X, Y); p[j] = other(k[j], X, Y); }
  prune_cleanup(k, p);
  #pragma unroll
  for (int j = 0; j < 8; ++j) { u64 X, Y; plswap32(k[j], X, Y); p[j] = other(k[j], X, Y); }
  prune_cleanup(k, p);

  // all lanes now hold the identical sorted top-8; lanes 0..7 store rank j
  #pragma unroll
  for (int j = 0; j < 8; ++j) {
    if (lane == j) {
      const uint u   = (uint)(k[j] >> 12);
      const uint cls = (~(uint)k[j]) & 0xFFFu;
      pk[(size_t)row * 8 + j] = make_int2(__float_as_int(finv(u)), (int)cls);
    }
  }
}

// ===========================================================================
// Pass 2: one wave per batch element. Sequential selection network over T
// (round-3-verified stage/direction structure, f64 max/min CEs), then a
// PARALLEL tail: LUT-composition backtrack + wave-parallel collapse.
// ===========================================================================

__device__ __forceinline__ uint composeLUT(uint A, uint B) {  // (A∘B)(w)=A[B[w]]
  uint R = 0;
  #pragma unroll
  for (int w = 0; w < 8; ++w) {
    const uint bw = (B >> (3 * w)) & 7u;
    const uint aw = (A >> (bw + (bw << 1))) & 7u;
    R |= aw << (3 * w);
  }
  return R;
}

__global__ __launch_bounds__(64) void ctc_pass2(const int2* __restrict__ pk,
                                                float* __restrict__ out) {
  __shared__ __align__(16) unsigned short bp[TT * TW];  // (parent<<9)|cls, 16 KB
  __shared__ float outb[TT];

  const int b    = blockIdx.x;
  const int lane = threadIdx.x;
  const int lo   = lane & 7;
  const int hi   = lane >> 3;
  const size_t base = (size_t)b * TT * 8;

  // pre-reversed load indices give alternating per-beam list directions
  const int idxB = (hi & 1) ? (7 - lo) : lo;   // even steps: beams along hi
  const int idxA = (lo & 1) ? (7 - hi) : hi;   // odd  steps: beams along lo
  const int2* ptrB = pk + base + idxB;
  const int2* ptrA = pk + base + idxA;

  // cleanup-direction booleans (loop-invariant; compiler hoists the masks)
  const bool dB1 = ((hi >> 1) & 1) == 0, dB2 = ((hi >> 2) & 1) == 0;
  const bool dA1 = ((lo >> 1) & 1) == 0, dA2 = ((lo >> 2) & 1) == 0;
  const bool l4 = (lo & 4) == 0, l2 = (lo & 2) == 0, l1 = (lo & 1) == 0;
  const bool h4 = (hi & 4) == 0, h2 = (hi & 2) == 0, h1 = (hi & 1) == 0;
  const bool kB1_4 = (l4 == dB1), kB1_2 = (l2 == dB1), kB1_1 = (l1 == dB1);
  const bool kB2_4 = (l4 == dB2), kB2_2 = (l2 == dB2), kB2_1 = (l1 == dB2);
  const bool kA1_4 = (h4 == dA1), kA1_2 = (h2 == dA1), kA1_1 = (h1 == dA1);
  const bool kA2_4 = (h4 == dA2), kA2_2 = (h2 == dA2), kA2_1 = (h1 == dA2);

  float s = (hi == 0) ? 0.0f : -1e30f;  // matches init_scores (step 0 = B step)

  int2 vB = ptrB[0],  vA = ptrA[8];
  int2 wB = ptrB[16], wA = ptrA[24];

  for (int t = 0; t < TT; t += 2) {
    const int tB = (t + 4 < TT) ? (t + 4) : (TT - 2);
    const int tA = (t + 5 < TT) ? (t + 5) : (TT - 1);
    const int2 nB = ptrB[tB * 8];
    const int2 nA = ptrA[tA * 8];

    // ---- step t (variant B: beams along hi, lists along lo) ----
    {
      const uint flat = ((uint)hi << 9) | (uint)vB.y;
      const uint tie  = (~flat) & 0xFFFu;
      const uint u    = ford(s + __int_as_float(vB.x));
      u64 K = KOFF | ((u64)u << 12) | tie;
      u64 P, X, Y;
      P = dppmov64<DPP_ROR8>(K); K = kmax(K, P);          // merge beams hi^1
      P = dpp_xor4(K);           K = ksel(K, P, kB1_4);
      P = dppmov64<DPP_XOR2>(K); K = ksel(K, P, kB1_2);
      P = dppmov64<DPP_XOR1>(K); K = ksel(K, P, kB1_1);
      plswap16(K, X, Y);         K = kmax(X, Y);          // merge mask 16
      P = dpp_xor4(K);           K = ksel(K, P, kB2_4);
      P = dppmov64<DPP_XOR2>(K); K = ksel(K, P, kB2_2);
      P = dppmov64<DPP_XOR1>(K); K = ksel(K, P, kB2_1);
      plswap32(K, X, Y);         K = kmax(X, Y);          // merge mask 32
      P = dpp_xor4(K);           K = ksel(K, P, l4);      // final sort: rank = lo
      P = dppmov64<DPP_XOR2>(K); K = ksel(K, P, l2);
      P = dppmov64<DPP_XOR1>(K); K = ksel(K, P, l1);
      if (hi == 0) bp[t * TW + lo] = (unsigned short)((~(uint)K) & 0xFFFu);
      s = finv((uint)(K >> 12));
    }
    // ---- step t+1 (variant A: beams along lo, lists along hi) ----
    {
      const uint flat = ((uint)lo << 9) | (uint)vA.y;
      const uint tie  = (~flat) & 0xFFFu;
      const uint u    = ford(s + __int_as_float(vA.x));
      u64 K = KOFF | ((u64)u << 12) | tie;
      u64 P, X, Y;
      P = dppmov64<DPP_XOR1>(K); K = kmax(K, P);          // merge beams lo^1
      plswap32(K, X, Y);         K = ksel(X, Y, kA1_4);
      plswap16(K, X, Y);         K = ksel(X, Y, kA1_2);
      P = dppmov64<DPP_ROR8>(K); K = ksel(K, P, kA1_1);
      P = dppmov64<DPP_XOR2>(K); K = kmax(K, P);          // merge mask 2
      plswap32(K, X, Y);         K = ksel(X, Y, kA2_4);
      plswap16(K, X, Y);         K = ksel(X, Y, kA2_2);
      P = dppmov64<DPP_ROR8>(K); K = ksel(K, P, kA2_1);
      P = dpp_xor4(K);           K = kmax(K, P);          // merge mask 4
      plswap32(K, X, Y);         K = ksel(X, Y, h4);      // final sort: rank = hi
      plswap16(K, X, Y);         K = ksel(X, Y, h2);
      P = dppmov64<DPP_ROR8>(K); K = ksel(K, P, h1);
      if (lo == 0) bp[(t + 1) * TW + hi] = (unsigned short)((~(uint)K) & 0xFFFu);
      s = finv((uint)(K >> 12));
    }
    vB = wB; vA = wA; wB = nB; wA = nA;
  }

  __syncthreads();

  // ---------------- parallel backtrack via LUT composition ----------------
  // lane covers t in [16*lane, 16*lane+15]. P[i] = parent-LUT at its t.
  uint P[16];
  uint D = 0xFAC688u;                       // identity LUT
  #pragma unroll
  for (int i = 0; i < 16; ++i) {
    const uint4 q = *reinterpret_cast<const uint4*>(&bp[(16 * lane + i) * 8]);
    uint Pi = 0;
    Pi |= ((q.x >>  9) & 7u) << 0;  Pi |= ((q.x >> 25) & 7u) << 3;
    Pi |= ((q.y >>  9) & 7u) << 6;  Pi |= ((q.y >> 25) & 7u) << 9;
    Pi |= ((q.z >>  9) & 7u) << 12; Pi |= ((q.z >> 25) & 7u) << 15;
    Pi |= ((q.w >>  9) & 7u) << 18; Pi |= ((q.w >> 25) & 7u) << 21;
    P[i] = Pi;
  }
  #pragma unroll
  for (int i = 15; i >= 0; --i) D = composeLUT(P[i], D);   // D = P0∘…∘P15 (chunk)

  // inclusive suffix scan of chunk maps: T_l = D_l ∘ D_{l+1} ∘ … ∘ D_63
  uint Tm = D;
  #pragma unroll
  for (int d = 1; d < 64; d <<= 1) {
    const uint O = __shfl_down(Tm, d, 64);
    const uint C = composeLUT(Tm, O);
    Tm = (lane + d < 64) ? C : Tm;
  }
  const uint Sm = __shfl_down(Tm, 1, 64);
  uint r = (lane == 63) ? 0u : (Sm & 7u);    // rank entering this chunk (top t)

  uint ridx[16];
  #pragma unroll
  for (int i = 15; i >= 0; --i) { ridx[i] = r; r = (P[i] >> (r + (r << 1))) & 7u; }

  int cls_arr[16];
  #pragma unroll
  for (int i = 0; i < 16; ++i)
    cls_arr[i] = bp[(16 * lane + i) * 8 + ridx[i]] & 511;

  // ---------------- wave-parallel CTC collapse ----------------
  // chunk-local last non-blank class (-1 if none), scanned across lanes
  int ln = -1;
  #pragma unroll
  for (int i = 0; i < 16; ++i) if (cls_arr[i] != 0) ln = cls_arr[i];
  int acc = ln;
  #pragma unroll
  for (int d = 1; d < 64; d <<= 1) {
    const int o = __shfl_up(acc, d, 64);
    if (lane >= d && acc == -1) acc = o;
  }
  int prev = __shfl_up(acc, 1, 64);
  if (lane == 0) prev = -1;

  int cnt = 0, keepm = 0;
  #pragma unroll
  for (int i = 0; i < 16; ++i) {
    const int c = cls_arr[i];
    const bool kp = (c != 0) && (c != prev);
    if (c != 0) prev = c;
    keepm |= (kp ? 1 : 0) << i;
    cnt += kp ? 1 : 0;
  }
  int sum = cnt;
  #pragma unroll
  for (int d = 1; d < 64; d <<= 1) {
    const int o = __shfl_up(sum, d, 64);
    if (lane >= d) sum += o;
  }
  const int total = __shfl(sum, 63, 64);
  int pos = sum - cnt;

  for (int i = lane; i < TT; i += 64) outb[i] = -1.0f;
  __syncthreads();
  #pragma unroll
  for (int i = 0; i < 16; ++i)
    if ((keepm >> i) & 1) outb[pos++] = (float)cls_arr[i];
  __syncthreads();

  float* dec = out + (size_t)b * TT;
  for (int i = lane; i < TT; i += 64) dec[i] = outb[i];
  if (lane == 0) {
    out[TB * TT + b]      = (float)total;  // lengths
    out[TB * TT + TB + b] = s;             // lane 0 holds rank-0 (beam 0) score
  }
}

extern "C" void kernel_launch(void* const* d_in, const int* in_sizes, int n_in,
                              void* d_out, int out_size, void* d_ws, size_t ws_size,
                              hipStream_t stream) {
  (void)in_sizes; (void)n_in; (void)out_size; (void)ws_size;
  const float* logits = (const float*)d_in[0];

  int2* pk = (int2*)d_ws;   // 64*1024*8 * 8 B = 4 MB packed {lp bits, cls}

  ctc_pass1<<<dim3((TB * TT) / 4), dim3(256), 0, stream>>>(logits, pk);
  ctc_pass2<<<dim3(TB), dim3(64), 0, stream>>>(pk, (float*)d_out);
}

// Round 8
// 494.654 us; speedup vs baseline: 8.8530x; 1.0414x over previous
//
#include <hip/hip_runtime.h>

#define TB 64
#define TT 1024
#define TC 512
#define TW 8

typedef unsigned long long u64;
typedef unsigned int uint;
typedef __attribute__((ext_vector_type(2))) unsigned int uint2v;

// ===========================================================================
// Native-f64 monotone keys (round-8): key = bits of (double)value, with the
// low 12 mantissa bits ORed with the tie field (flat = w*512+cls, or cls).
// All candidate values are STRICTLY NEGATIVE (log_softmax < 0 always, so
// every beam score and candidate < 0 from step 0 on). For negative reals a
// larger mantissa means a smaller value, so fmax prefers the SMALLER flat on
// value ties — exactly jax.lax.top_k's (value desc, index asc) order.
// Distinct f32 values differ by >= 2^29 f64-ulps >> 2^12 tie perturbation,
// so the tie bits can never flip a genuine value comparison. (double)f32 is
// exact with 29 low mantissa zeros; masking the low 12 bits restores the
// exact f64, and cvt back to f32 is exact.
// ===========================================================================

__device__ __forceinline__ double kd(u64 k) { return __longlong_as_double((long long)k); }
__device__ __forceinline__ u64 dk(double d) { return (u64)__double_as_longlong(d); }

__device__ __forceinline__ u64 kmax(u64 a, u64 b) { return dk(fmax(kd(a), kd(b))); }
__device__ __forceinline__ u64 kmin(u64 a, u64 b) { return dk(fmin(kd(a), kd(b))); }
// keep ? max : min  (operands may be an unordered pair)
__device__ __forceinline__ u64 ksel(u64 a, u64 b, bool keep) {
  double A = kd(a), B = kd(b);
  return dk(keep ? fmax(A, B) : fmin(A, B));
}

// pack: (f64)val | tie   (val < 0 f32; tie < 4096)
__device__ __forceinline__ u64 kpack(float val, uint tie) {
  return dk((double)val) | (u64)tie;
}
// unpack value (exact f32 round-trip)
__device__ __forceinline__ float kval(u64 k) {
  return (float)kd(k & ~0xFFFull);
}

#define DPP_XOR1  0xB1   // quad_perm [1,0,3,2]
#define DPP_XOR2  0x4E   // quad_perm [2,3,0,1]
#define DPP_XOR3  0x1B   // quad_perm [3,2,1,0]
#define DPP_HMIR  0x141  // row_half_mirror (xor 7)
#define DPP_ROR8  0x128  // row_ror:8 == xor 8 within a 16-lane row

template<int CTRL>
__device__ __forceinline__ u64 dppmov64(u64 x) {
  uint lo = (uint)__builtin_amdgcn_mov_dpp((int)(uint)x,         CTRL, 0xf, 0xf, true);
  uint hi = (uint)__builtin_amdgcn_mov_dpp((int)(uint)(x >> 32), CTRL, 0xf, 0xf, true);
  return ((u64)hi << 32) | lo;
}
__device__ __forceinline__ u64 dpp_xor4(u64 x) {          // xor3 then xor7 => xor4
  return dppmov64<DPP_HMIR>(dppmov64<DPP_XOR3>(x));
}

template<int CTRL>
__device__ __forceinline__ float dppf(float x) {
  return __uint_as_float((uint)__builtin_amdgcn_mov_dpp((int)__float_as_uint(x),
                                                        CTRL, 0xf, 0xf, true));
}
__device__ __forceinline__ float dppf_xor4(float x) {
  return dppf<DPP_HMIR>(dppf<DPP_XOR3>(x));
}

// permlane swaps via gfx950 builtins (round-7-verified sound primitive):
// returns the unordered pair {own, partner(lane^16/32)}.
__device__ __forceinline__ void plswap16(u64 k, u64& X, u64& Y) {
  const uint2v lo = __builtin_amdgcn_permlane16_swap((uint)k, (uint)k, false, false);
  const uint2v hi = __builtin_amdgcn_permlane16_swap((uint)(k >> 32), (uint)(k >> 32),
                                                     false, false);
  X = ((u64)hi[0] << 32) | lo[0];
  Y = ((u64)hi[1] << 32) | lo[1];
}
__device__ __forceinline__ void plswap32(u64 k, u64& X, u64& Y) {
  const uint2v lo = __builtin_amdgcn_permlane32_swap((uint)k, (uint)k, false, false);
  const uint2v hi = __builtin_amdgcn_permlane32_swap((uint)(k >> 32), (uint)(k >> 32),
                                                     false, false);
  X = ((u64)hi[0] << 32) | lo[0];
  Y = ((u64)hi[1] << 32) | lo[1];
}
__device__ __forceinline__ void plswap16f(float k, float& X, float& Y) {
  const uint2v r = __builtin_amdgcn_permlane16_swap(__float_as_uint(k),
                                                    __float_as_uint(k), false, false);
  X = __uint_as_float(r[0]); Y = __uint_as_float(r[1]);
}
__device__ __forceinline__ void plswap32f(float k, float& X, float& Y) {
  const uint2v r = __builtin_amdgcn_permlane32_swap(__float_as_uint(k),
                                                    __float_as_uint(k), false, false);
  X = __uint_as_float(r[0]); Y = __uint_as_float(r[1]);
}
// isolate the partner value from an unordered pair (keys are unique)
__device__ __forceinline__ u64 other(u64 own, u64 X, u64 Y) {
  return (X == own) ? Y : X;
}

// in-register compare-exchanges
__device__ __forceinline__ void ce_desc(u64& a, u64& b) {
  u64 mx = kmax(a, b), mn = kmin(a, b); a = mx; b = mn;
}
__device__ __forceinline__ void ce_asc(u64& a, u64& b) {
  u64 mx = kmax(a, b), mn = kmin(a, b); a = mn; b = mx;
}

// ===========================================================================
// Pass 1: per (b,t) row of 512 logits -> log_softmax -> top-8 sorted by
// (value desc, class asc). One wave/row. In-reg sort8 + 6-level cross-lane
// merge-prune tree; all-VALU. Output: raw u64 keys (f64(lp) | cls).
// ===========================================================================

// prune top-8 of two sorted-desc 8-lists (ours + partner's), re-sort desc.
__device__ __forceinline__ void prune_cleanup(u64 k[8], const u64 p[8]) {
  u64 c[8];
  #pragma unroll
  for (int j = 0; j < 8; ++j) c[j] = kmax(k[j], p[7 - j]);   // bitonic split
  ce_desc(c[0], c[4]); ce_desc(c[1], c[5]); ce_desc(c[2], c[6]); ce_desc(c[3], c[7]);
  ce_desc(c[0], c[2]); ce_desc(c[1], c[3]); ce_desc(c[4], c[6]); ce_desc(c[5], c[7]);
  ce_desc(c[0], c[1]); ce_desc(c[2], c[3]); ce_desc(c[4], c[5]); ce_desc(c[6], c[7]);
  #pragma unroll
  for (int j = 0; j < 8; ++j) k[j] = c[j];
}

__global__ __launch_bounds__(256) void ctc_pass1(const float* __restrict__ logits,
                                                 u64* __restrict__ pk) {
  const int lane = threadIdx.x & 63;
  const int row  = (blockIdx.x << 2) + (threadIdx.x >> 6);  // b*TT + t
  const float* src = logits + (size_t)row * TC;

  const float4 va = *reinterpret_cast<const float4*>(src + lane * 8);
  const float4 vb = *reinterpret_cast<const float4*>(src + lane * 8 + 4);
  float v[8] = {va.x, va.y, va.z, va.w, vb.x, vb.y, vb.z, vb.w};

  // row max — same butterfly partner pairing as verified rounds (bitwise stable)
  float m = v[0];
  #pragma unroll
  for (int j = 1; j < 8; ++j) m = fmaxf(m, v[j]);
  m = fmaxf(m, dppf<DPP_XOR1>(m));
  m = fmaxf(m, dppf<DPP_XOR2>(m));
  m = fmaxf(m, dppf_xor4(m));
  m = fmaxf(m, dppf<DPP_ROR8>(m));
  { float X, Y; plswap16f(m, X, Y); m = fmaxf(X, Y); }
  { float X, Y; plswap32f(m, X, Y); m = fmaxf(X, Y); }

  float sh[8];
  float sum = 0.f;
  #pragma unroll
  for (int j = 0; j < 8; ++j) { sh[j] = v[j] - m; sum += expf(sh[j]); }
  sum += dppf<DPP_XOR1>(sum);
  sum += dppf<DPP_XOR2>(sum);
  sum += dppf_xor4(sum);
  sum += dppf<DPP_ROR8>(sum);
  { float X, Y; plswap16f(sum, X, Y); sum = X + Y; }
  { float X, Y; plswap32f(sum, X, Y); sum = X + Y; }
  const float lse = logf(sum);

  // keys: f64(lp) | cls  — lp < 0 always, so smaller cls wins on f32 ties
  u64 k[8];
  #pragma unroll
  for (int j = 0; j < 8; ++j) {
    const float lp = sh[j] - lse;
    const uint cls = (uint)((lane << 3) + j);
    k[j] = kpack(lp, cls);
  }

  // bitonic sort8 desc (24 CEs)
  ce_desc(k[0], k[1]); ce_asc(k[2], k[3]); ce_desc(k[4], k[5]); ce_asc(k[6], k[7]);
  ce_desc(k[0], k[2]); ce_desc(k[1], k[3]); ce_asc(k[4], k[6]); ce_asc(k[5], k[7]);
  ce_desc(k[0], k[1]); ce_desc(k[2], k[3]); ce_asc(k[4], k[5]); ce_asc(k[6], k[7]);
  ce_desc(k[0], k[4]); ce_desc(k[1], k[5]); ce_desc(k[2], k[6]); ce_desc(k[3], k[7]);
  ce_desc(k[0], k[2]); ce_desc(k[1], k[3]); ce_desc(k[4], k[6]); ce_desc(k[5], k[7]);
  ce_desc(k[0], k[1]); ce_desc(k[2], k[3]); ce_desc(k[4], k[5]); ce_desc(k[6], k[7]);

  // 6-level cross-lane merge-prune (d = 1,2,4,8 via DPP; 16,32 via permlane)
  u64 p[8];
  #pragma unroll
  for (int j = 0; j < 8; ++j) p[j] = dppmov64<DPP_XOR1>(k[j]);
  prune_cleanup(k, p);
  #pragma unroll
  for (int j = 0; j < 8; ++j) p[j] = dppmov64<DPP_XOR2>(k[j]);
  prune_cleanup(k, p);
  #pragma unroll
  for (int j = 0; j < 8; ++j) p[j] = dpp_xor4(k[j]);
  prune_cleanup(k, p);
  #pragma unroll
  for (int j = 0; j < 8; ++j) p[j] = dppmov64<DPP_ROR8>(k[j]);
  prune_cleanup(k, p);
  #pragma unroll
  for (int j = 0; j < 8; ++j) { u64 X, Y; plswap16(k[j], X, Y); p[j] = other(k[j], X, Y); }
  prune_cleanup(k, p);
  #pragma unroll
  for (int j = 0; j < 8; ++j) { u64 X, Y; plswap32(k[j], X, Y); p[j] = other(k[j], X, Y); }
  prune_cleanup(k, p);

  // all lanes hold the identical sorted top-8; lanes 0..7 store rank j raw
  #pragma unroll
  for (int j = 0; j < 8; ++j) {
    if (lane == j) pk[(size_t)row * 8 + j] = k[j];
  }
}

// ===========================================================================
// Pass 2: one wave per batch element. Sequential selection network over T
// (round-3/7-verified stage/direction structure; f64 max/min CEs on native
// value keys), then the PARALLEL tail: LUT backtrack + wave collapse.
// ===========================================================================

__device__ __forceinline__ uint composeLUT(uint A, uint B) {  // (A∘B)(w)=A[B[w]]
  uint R = 0;
  #pragma unroll
  for (int w = 0; w < 8; ++w) {
    const uint bw = (B >> (3 * w)) & 7u;
    const uint aw = (A >> (bw + (bw << 1))) & 7u;
    R |= aw << (3 * w);
  }
  return R;
}

__global__ __launch_bounds__(64) void ctc_pass2(const u64* __restrict__ pk,
                                                float* __restrict__ out) {
  __shared__ __align__(16) unsigned short bp[TT * TW];  // (parent<<9)|cls, 16 KB
  __shared__ float outb[TT];

  const int b    = blockIdx.x;
  const int lane = threadIdx.x;
  const int lo   = lane & 7;
  const int hi   = lane >> 3;
  const size_t base = (size_t)b * TT * 8;

  // pre-reversed load indices give alternating per-beam list directions
  const int idxB = (hi & 1) ? (7 - lo) : lo;   // even steps: beams along hi
  const int idxA = (lo & 1) ? (7 - hi) : hi;   // odd  steps: beams along lo
  const u64* ptrB = pk + base + idxB;
  const u64* ptrA = pk + base + idxA;

  // cleanup-direction booleans (loop-invariant; compiler hoists the masks)
  const bool dB1 = ((hi >> 1) & 1) == 0, dB2 = ((hi >> 2) & 1) == 0;
  const bool dA1 = ((lo >> 1) & 1) == 0, dA2 = ((lo >> 2) & 1) == 0;
  const bool l4 = (lo & 4) == 0, l2 = (lo & 2) == 0, l1 = (lo & 1) == 0;
  const bool h4 = (hi & 4) == 0, h2 = (hi & 2) == 0, h1 = (hi & 1) == 0;
  const bool kB1_4 = (l4 == dB1), kB1_2 = (l2 == dB1), kB1_1 = (l1 == dB1);
  const bool kB2_4 = (l4 == dB2), kB2_2 = (l2 == dB2), kB2_1 = (l1 == dB2);
  const bool kA1_4 = (h4 == dA1), kA1_2 = (h2 == dA1), kA1_1 = (h1 == dA1);
  const bool kA2_4 = (h4 == dA2), kA2_2 = (h2 == dA2), kA2_1 = (h1 == dA2);

  float s = (hi == 0) ? 0.0f : -1e30f;  // matches init_scores (step 0 = B step)

  u64 vB = ptrB[0],  vA = ptrA[8];
  u64 wB = ptrB[16], wA = ptrA[24];

  for (int t = 0; t < TT; t += 2) {
    const int tB = (t + 4 < TT) ? (t + 4) : (TT - 2);
    const int tA = (t + 5 < TT) ? (t + 5) : (TT - 1);
    const u64 nB = ptrB[tB * 8];
    const u64 nA = ptrA[tA * 8];

    // ---- step t (variant B: beams along hi, lists along lo) ----
    {
      // off-chain prep (depends only on prefetched vB)
      const float lpB  = kval(vB);
      const uint  tieB = ((uint)vB & 0xFFFu) | ((uint)hi << 9);  // flat = w*512+cls
      // chain joins: cand -> key
      u64 K = kpack(s + lpB, tieB);
      u64 P, X, Y;
      P = dppmov64<DPP_ROR8>(K); K = kmax(K, P);          // merge beams hi^1
      P = dpp_xor4(K);           K = ksel(K, P, kB1_4);
      P = dppmov64<DPP_XOR2>(K); K = ksel(K, P, kB1_2);
      P = dppmov64<DPP_XOR1>(K); K = ksel(K, P, kB1_1);
      plswap16(K, X, Y);         K = kmax(X, Y);          // merge mask 16
      P = dpp_xor4(K);           K = ksel(K, P, kB2_4);
      P = dppmov64<DPP_XOR2>(K); K = ksel(K, P, kB2_2);
      P = dppmov64<DPP_XOR1>(K); K = ksel(K, P, kB2_1);
      plswap32(K, X, Y);         K = kmax(X, Y);          // merge mask 32
      P = dpp_xor4(K);           K = ksel(K, P, l4);      // final sort: rank = lo
      P = dppmov64<DPP_XOR2>(K); K = ksel(K, P, l2);
      P = dppmov64<DPP_XOR1>(K); K = ksel(K, P, l1);
      bp[t * TW + lo] = (unsigned short)((uint)K & 0xFFFu);  // all copies write same
      s = kval(K);
    }
    // ---- step t+1 (variant A: beams along lo, lists along hi) ----
    {
      const float lpA  = kval(vA);
      const uint  tieA = ((uint)vA & 0xFFFu) | ((uint)lo << 9);
      u64 K = kpack(s + lpA, tieA);
      u64 P, X, Y;
      P = dppmov64<DPP_XOR1>(K); K = kmax(K, P);          // merge beams lo^1
      plswap32(K, X, Y);         K = ksel(X, Y, kA1_4);
      plswap16(K, X, Y);         K = ksel(X, Y, kA1_2);
      P = dppmov64<DPP_ROR8>(K); K = ksel(K, P, kA1_1);
      P = dppmov64<DPP_XOR2>(K); K = kmax(K, P);          // merge mask 2
      plswap32(K, X, Y);         K = ksel(X, Y, kA2_4);
      plswap16(K, X, Y);         K = ksel(X, Y, kA2_2);
      P = dppmov64<DPP_ROR8>(K); K = ksel(K, P, kA2_1);
      P = dpp_xor4(K);           K = kmax(K, P);          // merge mask 4
      plswap32(K, X, Y);         K = ksel(X, Y, h4);      // final sort: rank = hi
      plswap16(K, X, Y);         K = ksel(X, Y, h2);
      P = dppmov64<DPP_ROR8>(K); K = ksel(K, P, h1);
      bp[(t + 1) * TW + hi] = (unsigned short)((uint)K & 0xFFFu);
      s = kval(K);
    }
    vB = wB; vA = wA; wB = nB; wA = nA;
  }

  __syncthreads();

  // ---------------- parallel backtrack via LUT composition ----------------
  // lane covers t in [16*lane, 16*lane+15]. P[i] = parent-LUT at its t.
  uint P[16];
  uint D = 0xFAC688u;                       // identity LUT
  #pragma unroll
  for (int i = 0; i < 16; ++i) {
    const uint4 q = *reinterpret_cast<const uint4*>(&bp[(16 * lane + i) * 8]);
    uint Pi = 0;
    Pi |= ((q.x >>  9) & 7u) << 0;  Pi |= ((q.x >> 25) & 7u) << 3;
    Pi |= ((q.y >>  9) & 7u) << 6;  Pi |= ((q.y >> 25) & 7u) << 9;
    Pi |= ((q.z >>  9) & 7u) << 12; Pi |= ((q.z >> 25) & 7u) << 15;
    Pi |= ((q.w >>  9) & 7u) << 18; Pi |= ((q.w >> 25) & 7u) << 21;
    P[i] = Pi;
  }
  #pragma unroll
  for (int i = 15; i >= 0; --i) D = composeLUT(P[i], D);   // D = P0∘…∘P15 (chunk)

  // inclusive suffix scan of chunk maps: T_l = D_l ∘ D_{l+1} ∘ … ∘ D_63
  uint Tm = D;
  #pragma unroll
  for (int d = 1; d < 64; d <<= 1) {
    const uint O = __shfl_down(Tm, d, 64);
    const uint C = composeLUT(Tm, O);
    Tm = (lane + d < 64) ? C : Tm;
  }
  const uint Sm = __shfl_down(Tm, 1, 64);
  uint r = (lane == 63) ? 0u : (Sm & 7u);    // rank entering this chunk (top t)

  uint ridx[16];
  #pragma unroll
  for (int i = 15; i >= 0; --i) { ridx[i] = r; r = (P[i] >> (r + (r << 1))) & 7u; }

  int cls_arr[16];
  #pragma unroll
  for (int i = 0; i < 16; ++i)
    cls_arr[i] = bp[(16 * lane + i) * 8 + ridx[i]] & 511;

  // ---------------- wave-parallel CTC collapse ----------------
  // chunk-local last non-blank class (-1 if none), scanned across lanes
  int ln = -1;
  #pragma unroll
  for (int i = 0; i < 16; ++i) if (cls_arr[i] != 0) ln = cls_arr[i];
  int acc = ln;
  #pragma unroll
  for (int d = 1; d < 64; d <<= 1) {
    const int o = __shfl_up(acc, d, 64);
    if (lane >= d && acc == -1) acc = o;
  }
  int prev = __shfl_up(acc, 1, 64);
  if (lane == 0) prev = -1;

  int cnt = 0, keepm = 0;
  #pragma unroll
  for (int i = 0; i < 16; ++i) {
    const int c = cls_arr[i];
    const bool kp = (c != 0) && (c != prev);
    if (c != 0) prev = c;
    keepm |= (kp ? 1 : 0) << i;
    cnt += kp ? 1 : 0;
  }
  int sum = cnt;
  #pragma unroll
  for (int d = 1; d < 64; d <<= 1) {
    const int o = __shfl_up(sum, d, 64);
    if (lane >= d) sum += o;
  }
  const int total = __shfl(sum, 63, 64);
  int pos = sum - cnt;

  for (int i = lane; i < TT; i += 64) outb[i] = -1.0f;
  __syncthreads();
  #pragma unroll
  for (int i = 0; i < 16; ++i)
    if ((keepm >> i) & 1) outb[pos++] = (float)cls_arr[i];
  __syncthreads();

  float* dec = out + (size_t)b * TT;
  for (int i = lane; i < TT; i += 64) dec[i] = outb[i];
  if (lane == 0) {
    out[TB * TT + b]      = (float)total;  // lengths
    out[TB * TT + TB + b] = s;             // lane 0 holds rank-0 (beam 0) score
  }
}

extern "C" void kernel_launch(void* const* d_in, const int* in_sizes, int n_in,
                              void* d_out, int out_size, void* d_ws, size_t ws_size,
                              hipStream_t stream) {
  (void)in_sizes; (void)n_in; (void)out_size; (void)ws_size;
  const float* logits = (const float*)d_in[0];

  u64* pk = (u64*)d_ws;   // 64*1024*8 * 8 B = 4 MB raw f64|tie keys

  ctc_pass1<<<dim3((TB * TT) / 4), dim3(256), 0, stream>>>(logits, pk);
  ctc_pass2<<<dim3(TB), dim3(64), 0, stream>>>(pk, (float*)d_out);
}